// Round 5
// baseline (448.343 us; speedup 1.0000x reference)
//
#include <hip/hip_runtime.h>
#include <hip/hip_bf16.h>
#include <stdint.h>

typedef __attribute__((ext_vector_type(8))) short short8;
typedef __attribute__((ext_vector_type(4))) float f32x4;

#define L2E 1.44269504f

static __device__ __forceinline__ short f2bf(float f) {
    unsigned int u = __float_as_uint(f);
    u += 0x7fffu + ((u >> 16) & 1u);   // RNE
    return (short)(u >> 16);
}

// w = exp2(lrelu(e1s + e2s)) if a>0 else 0; accumulate lsum; return bf16(w).
static __device__ __forceinline__ short welem(int a, float e2s, float e1s, float& lsum) {
    float x = e1s + e2s;
    x = fmaxf(x, 0.f) + 0.2f * fminf(x, 0.f);    // leaky relu (scale-invariant)
    float w = __builtin_amdgcn_exp2f(x);          // v_exp_f32 (2^x)
    w = (a > 0) ? w : 0.f;
    lsum += w;
    return f2bf(w);
}

// ---------------- Phase 1: Wh = h@W -> e1, e2 (fp32), whT in B-fragment tiles --
// W staged in LDS; 512 blocks x 4 waves x 4 rows. (r3 form, measured == r0.)
// whT layout (shorts): tile(=j>>6)*4096 + ((n>>4)*2 + frag)*512 + qk*128 + (n&15)*8 + t
//   where j = node, n = feature, kin = j&63, frag = kin>>5, qk = (kin>>3)&3, t = kin&7.
__global__ __launch_bounds__(256)
void gat_wh(const float* __restrict__ h, const float* __restrict__ W,
            const float* __restrict__ a, short* __restrict__ whT,
            float* __restrict__ e1, float* __restrict__ e2)
{
    __shared__ float sW[128][64];
    const int tid  = threadIdx.x;
    const int lane = tid & 63;
    const int wave = tid >> 6;
    const int row0 = blockIdx.x * 16 + wave * 4;

    float acc[4] = {0.f, 0.f, 0.f, 0.f};
#pragma unroll
    for (int t = 0; t < 4; ++t) {
        const int c0 = t * 128;
        {
            const float4* src = reinterpret_cast<const float4*>(W + c0 * 64);
            float4* dst = reinterpret_cast<float4*>(&sW[0][0]);
#pragma unroll
            for (int k = 0; k < 8; ++k) dst[tid + k * 256] = src[tid + k * 256];
        }
        __syncthreads();
#pragma unroll 4
        for (int ci = 0; ci < 128; ++ci) {
            const float wv = sW[ci][lane];
#pragma unroll
            for (int r = 0; r < 4; ++r)
                acc[r] += h[(size_t)(row0 + r) * 512 + c0 + ci] * wv;
        }
        __syncthreads();
    }

    const float a1v = a[lane];
    const float a2v = a[64 + lane];
    const int f    = lane >> 4;
    const int r16n = lane & 15;
#pragma unroll
    for (int r = 0; r < 4; ++r) {
        float p1 = acc[r] * a1v;
        float p2 = acc[r] * a2v;
#pragma unroll
        for (int off = 32; off; off >>= 1) {
            p1 += __shfl_xor(p1, off);
            p2 += __shfl_xor(p2, off);
        }
        if (lane == 0) { e1[row0 + r] = p1; e2[row0 + r] = p2; }
        const int j = row0 + r;
        const int kin = j & 63;
        const int frag = (kin >> 5) & 1, qk = (kin >> 3) & 3, t = kin & 7;
        whT[(size_t)(j >> 6) * 4096 + (f * 2 + frag) * 512 + qk * 128 + r16n * 8 + t]
            = f2bf(acc[r]);
    }
}

// ---------------- Phase 2: fused masked exp + P@Wh, FULL rows per block --------
// 512 blocks x 512 threads; block = 16 rows x all 8192 cols. Wave w owns the
// 1024-col slice [w*1024, (w+1)*1024) — per-wave work identical to the old
// sliced version — then an LDS cross-wave reduction replaces the old
// opart/lpart global round-trip (32 MB HBM) and the gat_combine kernel.
// Reduction order over w=0..7 equals the old combine's s=0..7 order ->
// bitwise-identical output. Chunk-loop body is the r3 (proven) form: direct
// int4 adj loads, compiler-scheduled; async/prefetch variants measured
// neutral-to-negative (r1/r2/r4).
__global__ __launch_bounds__(512)
void gat_attn(const int* __restrict__ adj, const short* __restrict__ whT,
              const float* __restrict__ e1, const float* __restrict__ e2,
              float* __restrict__ out)
{
    __shared__ float se2[8192];        // 32 KB: full e2 row, pre-scaled
    __shared__ float red[8][16][64];   // 32 KB: per-wave output tiles
    __shared__ float redl[8][16];      // per-wave denominator partials
    const int bid = blockIdx.x;
    const int tid = threadIdx.x;

    // stage e2 (all 8192), pre-scaled by log2(e): 4 x float4 per thread
#pragma unroll
    for (int k = 0; k < 4; ++k) {
        float4 v = *reinterpret_cast<const float4*>(e2 + k * 2048 + tid * 4);
        v.x *= L2E; v.y *= L2E; v.z *= L2E; v.w *= L2E;
        *reinterpret_cast<float4*>(se2 + k * 2048 + tid * 4) = v;
    }
    __syncthreads();

    const int lane = tid & 63;
    const int wave = tid >> 6;           // 8 waves = 8 col-slices
    const int quad = lane >> 4;
    const int r16  = lane & 15;
    const int rowBase = bid * 16;
    const int row  = rowBase + r16;
    const float e1s = e1[row] * L2E;
    const size_t adjRow = (size_t)row * 8192 + (size_t)wave * 1024;
    const float* se2w = se2 + wave * 1024;

    float lsum = 0.f;
    f32x4 acc[4];
#pragma unroll
    for (int ff = 0; ff < 4; ++ff) acc[ff] = (f32x4){0.f, 0.f, 0.f, 0.f};

    for (int ch = 0; ch < 16; ++ch) {
        const int j0 = ch * 64 + quad * 8;   // within-slice k-group for A-frag
        const int4 A0 = *reinterpret_cast<const int4*>(adj + adjRow + j0);
        const int4 A1 = *reinterpret_cast<const int4*>(adj + adjRow + j0 + 4);
        const int4 A2 = *reinterpret_cast<const int4*>(adj + adjRow + j0 + 32);
        const int4 A3 = *reinterpret_cast<const int4*>(adj + adjRow + j0 + 36);
        const float4 E0 = *reinterpret_cast<const float4*>(se2w + j0);
        const float4 E1 = *reinterpret_cast<const float4*>(se2w + j0 + 4);
        const float4 E2 = *reinterpret_cast<const float4*>(se2w + j0 + 32);
        const float4 E3 = *reinterpret_cast<const float4*>(se2w + j0 + 36);

        short8 af0, af1;
        af0[0] = welem(A0.x, E0.x, e1s, lsum);
        af0[1] = welem(A0.y, E0.y, e1s, lsum);
        af0[2] = welem(A0.z, E0.z, e1s, lsum);
        af0[3] = welem(A0.w, E0.w, e1s, lsum);
        af0[4] = welem(A1.x, E1.x, e1s, lsum);
        af0[5] = welem(A1.y, E1.y, e1s, lsum);
        af0[6] = welem(A1.z, E1.z, e1s, lsum);
        af0[7] = welem(A1.w, E1.w, e1s, lsum);
        af1[0] = welem(A2.x, E2.x, e1s, lsum);
        af1[1] = welem(A2.y, E2.y, e1s, lsum);
        af1[2] = welem(A2.z, E2.z, e1s, lsum);
        af1[3] = welem(A2.w, E2.w, e1s, lsum);
        af1[4] = welem(A3.x, E3.x, e1s, lsum);
        af1[5] = welem(A3.y, E3.y, e1s, lsum);
        af1[6] = welem(A3.z, E3.z, e1s, lsum);
        af1[7] = welem(A3.w, E3.w, e1s, lsum);

        // B-fragment loads: whT pre-permuted -> 64 lanes x 16 B contiguous
        const short* wtile = whT + (size_t)(wave * 16 + ch) * 4096 + lane * 8;
#pragma unroll
        for (int ff = 0; ff < 4; ++ff) {
            const short8 b0 = *reinterpret_cast<const short8*>(wtile + (ff * 2 + 0) * 512);
            const short8 b1 = *reinterpret_cast<const short8*>(wtile + (ff * 2 + 1) * 512);
            acc[ff] = __builtin_amdgcn_mfma_f32_16x16x32_bf16(af0, b0, acc[ff], 0, 0, 0);
            acc[ff] = __builtin_amdgcn_mfma_f32_16x16x32_bf16(af1, b1, acc[ff], 0, 0, 0);
        }
    }

    // wave-local denominator: reduce the 4 quads holding the same row
    lsum += __shfl_xor(lsum, 16);
    lsum += __shfl_xor(lsum, 32);
    if (lane < 16) redl[wave][lane] = lsum;

    // wave tile -> LDS
#pragma unroll
    for (int ff = 0; ff < 4; ++ff)
#pragma unroll
        for (int rg = 0; rg < 4; ++rg)
            red[wave][quad * 4 + rg][ff * 16 + r16] = acc[ff][rg];
    __syncthreads();

    // final cross-wave combine: 1024 outputs, 512 threads -> 2 each.
    // w ascending == old slice order s ascending -> bitwise-identical sums.
#pragma unroll
    for (int e = 0; e < 2; ++e) {
        const int idx = tid + e * 512;
        const int r = idx >> 6, f = idx & 63;
        float ls = 0.f, os = 0.f;
#pragma unroll
        for (int w = 0; w < 8; ++w) { ls += redl[w][r]; os += red[w][r][f]; }
        const float v = os / ls;
        out[(size_t)(rowBase + r) * 64 + f] = (v > 0.f) ? v : (__expf(v) - 1.f);
    }
}

extern "C" void kernel_launch(void* const* d_in, const int* in_sizes, int n_in,
                              void* d_out, int out_size, void* d_ws, size_t ws_size,
                              hipStream_t stream) {
    const float* h   = (const float*)d_in[0];
    const int*   adj = (const int*)d_in[1];
    const float* W   = (const float*)d_in[2];
    const float* a   = (const float*)d_in[3];
    float* out = (float*)d_out;

    char* ws = (char*)d_ws;
    short* whT = (short*)ws;                                   // 1 MB
    float* e1  = (float*)(ws + (1u << 20));                    // 32 KB
    float* e2  = (float*)(ws + (1u << 20) + (32u << 10));      // 32 KB

    gat_wh<<<512, 256, 0, stream>>>(h, W, a, whT, e1, e2);
    gat_attn<<<512, 512, 0, stream>>>(adj, whT, e1, e2, out);
}

// Round 6
// 432.770 us; speedup vs baseline: 1.0360x; 1.0360x over previous
//
#include <hip/hip_runtime.h>
#include <hip/hip_bf16.h>
#include <stdint.h>

typedef __attribute__((ext_vector_type(8))) short short8;
typedef __attribute__((ext_vector_type(4))) float f32x4;

#define NSLICE 8
#define SLICE_J 1024
#define CHUNKS 16   // SLICE_J / 64
#define L2E 1.44269504f

static __device__ __forceinline__ short f2bf(float f) {
    unsigned int u = __float_as_uint(f);
    u += 0x7fffu + ((u >> 16) & 1u);   // RNE
    return (short)(u >> 16);
}

// w = exp2(lrelu(e1s + e2s)) if a>0 else 0; accumulate lsum; return bf16(w).
static __device__ __forceinline__ short welem(int a, float e2s, float e1s, float& lsum) {
    float x = e1s + e2s;
    x = fmaxf(x, 0.f) + 0.2f * fminf(x, 0.f);    // leaky relu (scale-invariant)
    float w = __builtin_amdgcn_exp2f(x);          // v_exp_f32 (2^x)
    w = (a > 0) ? w : 0.f;
    lsum += w;
    return f2bf(w);
}

// ---------------- Phase 1: Wh = h@W -> e1, e2 (fp32), whT in B-fragment tiles --
// r3 form, reshaped 1024 blocks x 4 waves x 2 rows (was 512x4x4): doubles
// blocks/CU for the latency-bound wave-uniform h stream. Same per-row
// accumulation order -> bitwise-identical outputs.
// whT layout (shorts): tile(=j>>6)*4096 + ((n>>4)*2 + frag)*512 + qk*128 + (n&15)*8 + t
//   where j = node, n = feature, kin = j&63, frag = kin>>5, qk = (kin>>3)&3, t = kin&7.
__global__ __launch_bounds__(256)
void gat_wh(const float* __restrict__ h, const float* __restrict__ W,
            const float* __restrict__ a, short* __restrict__ whT,
            float* __restrict__ e1, float* __restrict__ e2)
{
    __shared__ float sW[128][64];
    const int tid  = threadIdx.x;
    const int lane = tid & 63;
    const int wave = tid >> 6;
    const int row0 = blockIdx.x * 8 + wave * 2;

    float acc[2] = {0.f, 0.f};
#pragma unroll
    for (int t = 0; t < 4; ++t) {
        const int c0 = t * 128;
        {
            const float4* src = reinterpret_cast<const float4*>(W + c0 * 64);
            float4* dst = reinterpret_cast<float4*>(&sW[0][0]);
#pragma unroll
            for (int k = 0; k < 8; ++k) dst[tid + k * 256] = src[tid + k * 256];
        }
        __syncthreads();
#pragma unroll 8
        for (int ci = 0; ci < 128; ++ci) {
            const float wv = sW[ci][lane];
#pragma unroll
            for (int r = 0; r < 2; ++r)                 // h index wave-uniform -> s_load
                acc[r] += h[(size_t)(row0 + r) * 512 + c0 + ci] * wv;
        }
        __syncthreads();
    }

    const float a1v = a[lane];
    const float a2v = a[64 + lane];
    const int f    = lane >> 4;
    const int r16n = lane & 15;
#pragma unroll
    for (int r = 0; r < 2; ++r) {
        float p1 = acc[r] * a1v;
        float p2 = acc[r] * a2v;
#pragma unroll
        for (int off = 32; off; off >>= 1) {
            p1 += __shfl_xor(p1, off);
            p2 += __shfl_xor(p2, off);
        }
        if (lane == 0) { e1[row0 + r] = p1; e2[row0 + r] = p2; }
        const int j = row0 + r;
        const int kin = j & 63;
        const int frag = (kin >> 5) & 1, qk = (kin >> 3) & 3, t = kin & 7;
        whT[(size_t)(j >> 6) * 4096 + (f * 2 + frag) * 512 + qk * 128 + r16n * 8 + t]
            = f2bf(acc[r]);
    }
}

// ---------------- Phase 2: fused masked exp + P@Wh (no-max softmax, split-j) --
// r3/r0 proven form, byte-for-byte: direct int4 adj loads, compiler-scheduled.
// Measured equal to async-LDS pipeline (r4) and better than fused rows (r5) --
// the adj stream is BW-saturated (~16 MB in flight >> 2.4 MB Little's-law
// threshold), so structural variants only move overhead around.
__global__ __launch_bounds__(256)
void gat_attn(const int* __restrict__ adj, const short* __restrict__ whT,
              const float* __restrict__ e1, const float* __restrict__ e2,
              float* __restrict__ lpart, float* __restrict__ opart)
{
    __shared__ float se2[SLICE_J];
    const int bid = blockIdx.x;
    const int s   = bid & (NSLICE - 1);
    const int rb  = bid >> 3;
    const int tid = threadIdx.x;

    // stage e2 slice into LDS, pre-scaled by log2(e)
    {
        float4 v = *reinterpret_cast<const float4*>(e2 + s * SLICE_J + tid * 4);
        v.x *= L2E; v.y *= L2E; v.z *= L2E; v.w *= L2E;
        *reinterpret_cast<float4*>(se2 + tid * 4) = v;
    }
    __syncthreads();

    const int lane = tid & 63;
    const int wave = tid >> 6;
    const int quad = lane >> 4;
    const int r16  = lane & 15;
    const int rowBase = rb * 64 + wave * 16;
    const int row  = rowBase + r16;
    const float e1s = e1[row] * L2E;
    const size_t adjRow = (size_t)row * 8192 + (size_t)s * SLICE_J;

    float lsum = 0.f;
    f32x4 acc[4];
#pragma unroll
    for (int ff = 0; ff < 4; ++ff) acc[ff] = (f32x4){0.f, 0.f, 0.f, 0.f};

    for (int ch = 0; ch < CHUNKS; ++ch) {
        const int j0 = ch * 64 + quad * 8;   // within-slice k-group for A-frag
        // adj directly in MFMA A-fragment layout: m=r16, k=quad*8+t (+32 for frag1)
        const int4 A0 = *reinterpret_cast<const int4*>(adj + adjRow + j0);
        const int4 A1 = *reinterpret_cast<const int4*>(adj + adjRow + j0 + 4);
        const int4 A2 = *reinterpret_cast<const int4*>(adj + adjRow + j0 + 32);
        const int4 A3 = *reinterpret_cast<const int4*>(adj + adjRow + j0 + 36);
        const float4 E0 = *reinterpret_cast<const float4*>(se2 + j0);
        const float4 E1 = *reinterpret_cast<const float4*>(se2 + j0 + 4);
        const float4 E2 = *reinterpret_cast<const float4*>(se2 + j0 + 32);
        const float4 E3 = *reinterpret_cast<const float4*>(se2 + j0 + 36);

        short8 af0, af1;
        af0[0] = welem(A0.x, E0.x, e1s, lsum);
        af0[1] = welem(A0.y, E0.y, e1s, lsum);
        af0[2] = welem(A0.z, E0.z, e1s, lsum);
        af0[3] = welem(A0.w, E0.w, e1s, lsum);
        af0[4] = welem(A1.x, E1.x, e1s, lsum);
        af0[5] = welem(A1.y, E1.y, e1s, lsum);
        af0[6] = welem(A1.z, E1.z, e1s, lsum);
        af0[7] = welem(A1.w, E1.w, e1s, lsum);
        af1[0] = welem(A2.x, E2.x, e1s, lsum);
        af1[1] = welem(A2.y, E2.y, e1s, lsum);
        af1[2] = welem(A2.z, E2.z, e1s, lsum);
        af1[3] = welem(A2.w, E2.w, e1s, lsum);
        af1[4] = welem(A3.x, E3.x, e1s, lsum);
        af1[5] = welem(A3.y, E3.y, e1s, lsum);
        af1[6] = welem(A3.z, E3.z, e1s, lsum);
        af1[7] = welem(A3.w, E3.w, e1s, lsum);

        // B-fragment loads: whT pre-permuted -> 64 lanes x 16 B contiguous per load
        const short* wtile = whT + (size_t)(s * 16 + ch) * 4096 + lane * 8;
#pragma unroll
        for (int ff = 0; ff < 4; ++ff) {
            const short8 b0 = *reinterpret_cast<const short8*>(wtile + (ff * 2 + 0) * 512);
            const short8 b1 = *reinterpret_cast<const short8*>(wtile + (ff * 2 + 1) * 512);
            acc[ff] = __builtin_amdgcn_mfma_f32_16x16x32_bf16(af0, b0, acc[ff], 0, 0, 0);
            acc[ff] = __builtin_amdgcn_mfma_f32_16x16x32_bf16(af1, b1, acc[ff], 0, 0, 0);
        }
    }

    // denominator partial: reduce across the 4 quads holding the same row
    lsum += __shfl_xor(lsum, 16);
    lsum += __shfl_xor(lsum, 32);
    if (lane < 16) lpart[s * 8192 + rowBase + lane] = lsum;

#pragma unroll
    for (int ff = 0; ff < 4; ++ff) {
#pragma unroll
        for (int rg = 0; rg < 4; ++rg) {
            const int orow = rowBase + quad * 4 + rg;
            const int ocol = ff * 16 + r16;
            opart[((size_t)s * 8192 + orow) * 64 + ocol] = acc[ff][rg];
        }
    }
}

// ---------------- Phase 3: merge slice partials, normalize, ELU ----------------
__global__ __launch_bounds__(256)
void gat_combine(const float* __restrict__ lpart, const float* __restrict__ opart,
                 float* __restrict__ out)
{
    const int gid = blockIdx.x * 256 + threadIdx.x;
    const int row = gid >> 6;
    const int f   = gid & 63;

    float lsum = 0.f, osum = 0.f;
#pragma unroll
    for (int s = 0; s < NSLICE; ++s) {
        lsum += lpart[s * 8192 + row];
        osum += opart[((size_t)s * 8192 + row) * 64 + f];
    }
    const float v = osum / lsum;
    out[gid] = (v > 0.f) ? v : (__expf(v) - 1.f);
}

extern "C" void kernel_launch(void* const* d_in, const int* in_sizes, int n_in,
                              void* d_out, int out_size, void* d_ws, size_t ws_size,
                              hipStream_t stream) {
    const float* h   = (const float*)d_in[0];
    const int*   adj = (const int*)d_in[1];
    const float* W   = (const float*)d_in[2];
    const float* a   = (const float*)d_in[3];
    float* out = (float*)d_out;

    char* ws = (char*)d_ws;
    short* whT   = (short*)ws;                                   // 1 MB
    float* e1    = (float*)(ws + (1u << 20));                    // 32 KB
    float* e2    = (float*)(ws + (1u << 20) + (32u << 10));      // 32 KB
    float* lpart = (float*)(ws + (1u << 20) + (64u << 10));      // 256 KB
    float* opart = (float*)(ws + (2u << 20));                    // 16 MB

    gat_wh<<<1024, 256, 0, stream>>>(h, W, a, whT, e1, e2);
    gat_attn<<<128 * NSLICE, 256, 0, stream>>>(adj, whT, e1, e2, lpart, opart);
    gat_combine<<<out_size / 256, 256, 0, stream>>>(lpart, opart, out);
}